// Round 1
// 81.354 us; speedup vs baseline: 1.1468x; 1.1468x over previous
//
#include <hip/hip_runtime.h>
#include <hip/hip_bf16.h>

#define SLEN 2048
#define FDIM 128
#define NH   16
#define NBH  32   // B*H = 2*16
#define QBLK 64   // q rows per attn tile (2 q-blocks x 32)
#define KVB  64   // kv rows per staged tile (2 k-slices x 32)
#define NQT  (SLEN / QBLK)   // 32

typedef __attribute__((ext_vector_type(8)))  __bf16 bf16x8;
typedef __attribute__((ext_vector_type(8)))  short  s16x8;
typedef __attribute__((ext_vector_type(4)))  short  s16x4;
typedef __attribute__((ext_vector_type(4)))  float  f32x4;
typedef __attribute__((ext_vector_type(16))) float  f32x16;
typedef __attribute__((ext_vector_type(4)))  int    i32x4;

__device__ __forceinline__ unsigned short f2bf_u(float f) {
    union { float f; unsigned u; } t;
    t.f = f;
    unsigned r = t.u + 0x7FFFu + ((t.u >> 16) & 1u);  // RNE
    return (unsigned short)(r >> 16);
}
__device__ __forceinline__ short f2bf(float f) { return (short)f2bf_u(f); }

// Packed f32->bf16 RNE conversion (1 instr for 2 values; low = first arg).
__device__ __forceinline__ unsigned cvt_pk_bf16(float lo, float hi) {
    unsigned r;
    asm("v_cvt_pk_bf16_f32 %0, %1, %2" : "=v"(r) : "v"(lo), "v"(hi));
    return r;
}

// exp2 via native transcendental (ISA: v_exp_f32: D = 2^S0).
__device__ __forceinline__ float ex2(float x) {
    float r;
    asm volatile("v_exp_f32 %0, %1" : "=v"(r) : "v"(x));
    return r;
}

// Direct global->LDS async copy, 16B per lane.
__device__ __forceinline__ void gld16(const void* g, void* l) {
    __builtin_amdgcn_global_load_lds(
        (const __attribute__((address_space(1))) void*)g,
        (__attribute__((address_space(3))) void*)l, 16, 0, 0);
}

// ---------------------------------------------------------------------------
// W pre-convert: f32 -> bf16, stored XOR-swizzled so qkv_fused can stage it
// with global_load_lds (linear LDS dest) and read fragments conflict-free:
//   Wb[z][h][ (e*128 + c) ^ ((e&15)<<3) ] = bf16(W_z[h][e][c])
// ---------------------------------------------------------------------------
__global__ __launch_bounds__(256, 4) void wconv(
    const float* __restrict__ Wq, const float* __restrict__ Wk,
    const float* __restrict__ Wv, short* __restrict__ Wb)
{
    const int bid = blockIdx.x;          // 192 blocks: 3 z x 16 h x 4 row-quads
    const int z = bid >> 6, rem = bid & 63;
    const int h = rem >> 2, qd = rem & 3;
    const float* Wm = ((z == 0) ? Wq : (z == 1) ? Wk : Wv) + (size_t)h * 16384;
    short* O = Wb + ((size_t)z * NH + h) * 16384;
    const int t = threadIdx.x;
    #pragma unroll
    for (int it = 0; it < 2; ++it) {
        int idx = qd * 4096 + it * 2048 + t * 8;   // short index within matrix
        int e = idx >> 7, c = idx & 127;
        f32x4 a = *(const f32x4*)&Wm[idx];
        f32x4 b = *(const f32x4*)&Wm[idx + 4];
        union { unsigned u[4]; s16x8 v; } o;
        o.u[0] = cvt_pk_bf16(a[0], a[1]);
        o.u[1] = cvt_pk_bf16(a[2], a[3]);
        o.u[2] = cvt_pk_bf16(b[0], b[1]);
        o.u[3] = cvt_pk_bf16(b[2], b[3]);
        *(s16x8*)&O[(e << 7) | (c ^ ((e & 15) << 3))] = o.v;
    }
}

// ---------------------------------------------------------------------------
// Fused QKV projection: one block per (st, bh); x tile staged+converted ONCE,
// then 3 GEMM phases (z = Q,K,V) with W staged bf16 via global_load_lds from
// the pre-swizzled Wb (ds_read applies the XOR; 2-way bank alias = free).
// Output layouts unchanged from round-17 (Q plain pre-scaled, K swizzled,
// V fragment-major with sigma baked in).
// ---------------------------------------------------------------------------
__global__ __launch_bounds__(256, 2) void qkv_fused(
    const float* __restrict__ x, const short* __restrict__ Wb,
    const float* __restrict__ bq, const float* __restrict__ bk, const float* __restrict__ bv,
    short* __restrict__ Q, short* __restrict__ K, short* __restrict__ Vt)
{
    const int bh = blockIdx.y;
    const int h  = bh & (NH - 1);
    const int st = blockIdx.x;
    const float* xg = x + ((size_t)bh * SLEN + st * 64) * FDIM;

    __shared__ __align__(16) short lx[64][136];   // padded (manual stores)
    __shared__ __align__(16) short lw[128][128];  // linear (gld16 dest), swizzled content

    const int t = threadIdx.x;
    const int wid = t >> 6, lane = t & 63;

    #define WSTAGE(zz) do {                                                     \
        const char* wsrc_ = (const char*)(Wb + ((size_t)(zz) * NH + h) * 16384);\
        _Pragma("unroll")                                                       \
        for (int i_ = 0; i_ < 8; ++i_)                                          \
            gld16(wsrc_ + wid * 8192 + i_ * 1024 + lane * 16,                   \
                  (char*)&lw[0][0] + wid * 8192 + i_ * 1024);                   \
    } while (0)

    WSTAGE(0);
    {   // stage x tile (f32 -> bf16), once for all three z
        int r = t >> 4, c = (t & 15) * 8;
        #pragma unroll
        for (int it = 0; it < 4; ++it) {
            const float* src = &xg[(size_t)(r + it * 16) * FDIM + c];
            f32x4 a = *(const f32x4*)&src[0];
            f32x4 b = *(const f32x4*)&src[4];
            union { unsigned u[4]; s16x8 v; } o;
            o.u[0] = cvt_pk_bf16(a[0], a[1]);
            o.u[1] = cvt_pk_bf16(a[2], a[3]);
            o.u[2] = cvt_pk_bf16(b[0], b[1]);
            o.u[3] = cvt_pk_bf16(b[2], b[3]);
            *(s16x8*)&lx[r + it * 16][c] = o.v;
        }
    }
    __syncthreads();

    const int wr = (wid >> 1) * 32;
    const int wc = (wid & 1) * 64;
    const int lr = lane & 15, lk = (lane >> 4) * 8, hi4 = (lane >> 4) * 4;
    const short* lwp = &lw[0][0];
    const int swz = lr << 3;

    #pragma unroll
    for (int z = 0; z < 3; ++z) {
        f32x4 acc[2][4] = {};
        #pragma unroll
        for (int ks = 0; ks < 4; ++ks) {
            int kb = ks * 32 + lk;
            bf16x8 a[2], b[4];
            #pragma unroll
            for (int m = 0; m < 2; ++m) a[m] = *(const bf16x8*)&lx[wr + m * 16 + lr][kb];
            #pragma unroll
            for (int n = 0; n < 4; ++n)
                b[n] = *(const bf16x8*)&lwp[(size_t)(wc + n * 16 + lr) * 128 + (kb ^ swz)];
            #pragma unroll
            for (int m = 0; m < 2; ++m)
                #pragma unroll
                for (int n = 0; n < 4; ++n)
                    acc[m][n] = __builtin_amdgcn_mfma_f32_16x16x32_bf16(a[m], b[n], acc[m][n], 0, 0, 0);
        }
        // all waves done reading lw for this z -> safe to overwrite
        if (z < 2) { __syncthreads(); WSTAGE(z + 1); }

        const float* bias = ((z == 0) ? bq : (z == 1) ? bk : bv) + h * FDIM;
        if (z == 0) {
            short* og = Q + ((size_t)bh * SLEN + st * 64) * FDIM;
            const float sc = 0.12751744526f;  // log2(e)/sqrt(128)
            #pragma unroll
            for (int n = 0; n < 4; ++n) {
                int col = wc + n * 16 + lr;
                float bb = bias[col];
                #pragma unroll
                for (int m = 0; m < 2; ++m) {
                    int r0 = wr + m * 16 + hi4;
                    #pragma unroll
                    for (int j = 0; j < 4; ++j)
                        og[(size_t)(r0 + j) * FDIM + col] = f2bf((acc[m][n][j] + bb) * sc);
                }
            }
        } else if (z == 1) {
            short* og = K + (size_t)bh * SLEN * FDIM;
            #pragma unroll
            for (int n = 0; n < 4; ++n) {
                int col = wc + n * 16 + lr;
                float bb = bias[col];
                #pragma unroll
                for (int m = 0; m < 2; ++m) {
                    int s0 = st * 64 + wr + m * 16 + hi4;
                    #pragma unroll
                    for (int j = 0; j < 4; ++j) {
                        int s = s0 + j;
                        int idx = (s * FDIM + col) ^ ((s & 15) << 3);
                        og[idx] = f2bf(acc[m][n][j] + bb);
                    }
                }
            }
        } else {
            short* ogT = Vt + (size_t)bh * SLEN * FDIM;
            const int hp = (hi4 == 4) ? 8 : (hi4 == 8) ? 4 : hi4;
            #pragma unroll
            for (int n = 0; n < 4; ++n) {
                int col = wc + n * 16 + lr;
                float bb = bias[col];
                const int cb  = col >> 5, qlp = col & 31;
                #pragma unroll
                for (int m = 0; m < 2; ++m) {
                    const int kb16 = wr + m * 16;
                    const int hs_  = kb16 >> 5;
                    const int s2_  = (kb16 >> 4) & 1;
                    const int hi2_ = hp >> 3;
                    const int j0   = hp & 7;
                    union { unsigned u[2]; s16x4 v; } w;
                    w.u[0] = cvt_pk_bf16(acc[m][n][0] + bb, acc[m][n][1] + bb);
                    w.u[1] = cvt_pk_bf16(acc[m][n][2] + bb, acc[m][n][3] + bb);
                    size_t addr = (size_t)st * 8192 + hs_ * 4096 + cb * 1024
                                + s2_ * 512 + (hi2_ * 32 + qlp) * 8 + j0;
                    *(s16x4*)&ogT[addr] = w.v;
                }
            }
        }
        if (z < 2) __syncthreads();   // W(z+1) gld16 drained by barrier's vmcnt(0)
    }
    #undef WSTAGE
}

// ---------------------------------------------------------------------------
// Causal flash attention (round-18):
//  - balanced qt remap: each CU's four resident blocks get qt summing to 66
//    steps ({31-j, 8+j, 23-j, j}), same bh per CU, longest-first preserved
//  - P->bf16 pack via v_cvt_pk_bf16_f32 (8 instrs vs ~70 integer-RNE ops)
//  - defer-max threshold 8 (exp2 domain): skip oacc rescale unless the max
//    grew by >8; P bounded by 2^8, f32 accumulate unaffected
// ---------------------------------------------------------------------------
__global__ __launch_bounds__(256, 2) void attn_fwd(
    const short* __restrict__ Qg, const short* __restrict__ Kg,
    const short* __restrict__ vTg, float* __restrict__ out)
{
    __shared__ __align__(16) char smem[34816];
    // K tile buf b: smem + b*16384 ([64][128] shorts, swizzled ^((s&15)<<3))
    float* obuf = (float*)smem;              // merge [2][32][132] f32 (aliases K bufs)
    float* mlb  = (float*)(smem + 33792);    // merge [4][32][2]   f32

    const int bid = blockIdx.x;
    const int bh  = bid & 31;
    // per-CU balanced qt assignment (CU gets bids {c, c+256, c+512, c+768})
    const int i   = ((bid >> 5) & 7) + ((bid >> 8) << 3);
    const int grp = i >> 3, k = i & 7;
    const int qt  = (grp == 0) ? (31 - k) : (grp == 1) ? (8 + k)
                  : (grp == 2) ? (23 - k) : k;

    const int t = threadIdx.x, wid = t >> 6, lane = t & 63;
    const int ql  = lane & 31;
    const int hi2 = lane >> 5;
    const int qb  = wid & 1;           // q-block (32 rows)
    const int hs  = wid >> 1;          // k-slice (32 of 64)
    const size_t base = (size_t)bh * SLEN * FDIM;

    const char*  kgb = (const char*)(Kg + base);
    const short* vgb = vTg + base + hs * 4096 + (size_t)lane * 8;

    bf16x8 qf[8];
    {
        const short* qp = Qg + base + (size_t)(qt * QBLK + qb * 32 + ql) * FDIM;
        #pragma unroll
        for (int ks = 0; ks < 8; ++ks) qf[ks] = *(const bf16x8*)&qp[ks * 16 + hi2 * 8];
    }

    f32x16 oacc[4] = {};
    float m_run = -1e30f, l_run = 0.f;

    #define STAGE(ktile, buf) do {                                               \
        const char* kt_ = kgb + (size_t)(ktile) * 16384;                         \
        _Pragma("unroll")                                                        \
        for (int i_ = 0; i_ < 4; ++i_)                                           \
            gld16(kt_ + wid * 4096 + i_ * 1024 + lane * 16,                      \
                  smem + (buf) * 16384 + wid * 4096 + i_ * 1024);                \
    } while (0)

    STAGE(0, 0);
    __syncthreads();

    const int nkt = qt + 1;
    int cur = 0;
    const int kswz = (ql & 15) << 3;

    for (int kt = 0; kt < nkt; ++kt) {
        // ---- issue this step's V fragment loads (consumed after softmax) ----
        bf16x8 vfr[8];
        {
            const short* vb_ = vgb + (size_t)kt * 8192;
            #pragma unroll
            for (int cb = 0; cb < 4; ++cb) {
                vfr[cb * 2 + 0] = *(const bf16x8*)&vb_[cb * 1024];
                vfr[cb * 2 + 1] = *(const bf16x8*)&vb_[cb * 1024 + 512];
            }
        }
        // ---- issue next K tile's async copy ----
        if (kt + 1 < nkt) STAGE(kt + 1, cur ^ 1);

        const char* kbuf = smem + cur * 16384;

        // ---- S^T = K Q^T ----
        const int Rrow = hs * 32 + ql;
        f32x16 sfr = {};
        __builtin_amdgcn_s_setprio(1);
        #pragma unroll
        for (int ks = 0; ks < 8; ++ks) {
            bf16x8 kf = *(const bf16x8*)(kbuf + (size_t)(((Rrow * 128 + ks * 16 + hi2 * 8) ^ kswz) * 2));
            sfr = __builtin_amdgcn_mfma_f32_32x32x16_bf16(kf, qf[ks], sfr, 0, 0, 0);
        }
        __builtin_amdgcn_s_setprio(0);

        // ---- causal mask (diag tile only) ----
        if (kt == qt) {
            if (hs > qb) {
                #pragma unroll
                for (int r = 0; r < 16; ++r) sfr[r] = -__builtin_inff();
            } else if (hs == qb) {
                #pragma unroll
                for (int r = 0; r < 16; ++r) {
                    int kl = (r & 3) + 8 * (r >> 2) + 4 * hi2;
                    if (kl > ql) sfr[r] = -__builtin_inff();
                }
            }
        }

        // ---- lane-local online softmax (exp2 domain), defer-max THR=8 ----
        float a0 = fmaxf(fmaxf(sfr[0],  sfr[1]),  sfr[2]);
        float a1 = fmaxf(fmaxf(sfr[3],  sfr[4]),  sfr[5]);
        float a2 = fmaxf(fmaxf(sfr[6],  sfr[7]),  sfr[8]);
        float a3 = fmaxf(fmaxf(sfr[9],  sfr[10]), sfr[11]);
        float a4 = fmaxf(fmaxf(sfr[12], sfr[13]), sfr[14]);
        float b0 = fmaxf(fmaxf(a0, a1), a2);
        float b1 = fmaxf(fmaxf(a3, a4), sfr[15]);
        float rm = fmaxf(b0, b1);
        rm = fmaxf(rm, __shfl_xor(rm, 32));
        if (!__all(rm <= m_run + 8.f)) {
            float mnew = fmaxf(m_run, rm);
            float fac  = ex2(m_run - mnew);
            l_run *= fac;
            #pragma unroll
            for (int cb = 0; cb < 4; ++cb) oacc[cb] *= fac;
            m_run = mnew;
        }
        float pe[16];
        #pragma unroll
        for (int r = 0; r < 16; ++r) pe[r] = ex2(sfr[r] - m_run);
        float s0 = (pe[0] + pe[1]) + (pe[2] + pe[3]);
        float s1 = (pe[4] + pe[5]) + (pe[6] + pe[7]);
        float s2 = (pe[8] + pe[9]) + (pe[10] + pe[11]);
        float s3 = (pe[12] + pe[13]) + (pe[14] + pe[15]);
        float ssum = (s0 + s1) + (s2 + s3);
        l_run += ssum + __shfl_xor(ssum, 32);

        // ---- pack P -> bf16 B-frags via v_cvt_pk_bf16_f32 ----
        bf16x8 pf[2];
        #pragma unroll
        for (int s2_ = 0; s2_ < 2; ++s2_) {
            const int b = s2_ * 8;
            union { unsigned u[4]; bf16x8 v; } w;
            w.u[0] = cvt_pk_bf16(pe[b + 0], pe[b + 1]);
            w.u[1] = cvt_pk_bf16(pe[b + 2], pe[b + 3]);
            w.u[2] = cvt_pk_bf16(pe[b + 4], pe[b + 5]);
            w.u[3] = cvt_pk_bf16(pe[b + 6], pe[b + 7]);
            pf[s2_] = w.v;
        }

        // ---- O^T += V^T P : V fragments already in registers ----
        __builtin_amdgcn_s_setprio(1);
        #pragma unroll
        for (int cb = 0; cb < 4; ++cb) {
            #pragma unroll
            for (int s2_ = 0; s2_ < 2; ++s2_)
                oacc[cb] = __builtin_amdgcn_mfma_f32_32x32x16_bf16(vfr[cb * 2 + s2_], pf[s2_], oacc[cb], 0, 0, 0);
        }
        __builtin_amdgcn_s_setprio(0);

        __syncthreads();   // next-K drained + cur-buf reads done
        cur ^= 1;
    }
    #undef STAGE

    // ---- merge of the two k-slices (waves hs=0 <- hs=1), exp2 domain ----
    if (lane < 32) {
        mlb[(wid * 32 + ql) * 2 + 0] = m_run;
        mlb[(wid * 32 + ql) * 2 + 1] = l_run;
    }
    if (hs == 1) {
        #pragma unroll
        for (int cb = 0; cb < 4; ++cb)
            #pragma unroll
            for (int r = 0; r < 16; ++r) {
                int e = cb * 32 + (r & 3) + 8 * (r >> 2) + 4 * hi2;
                obuf[(qb * 32 + ql) * 132 + e] = oacc[cb][r];
            }
    }
    __syncthreads();
    if (hs == 0) {
        float m2 = mlb[((wid + 2) * 32 + ql) * 2 + 0];
        float l2 = mlb[((wid + 2) * 32 + ql) * 2 + 1];
        float M  = fmaxf(m_run, m2);
        float a  = ex2(m_run - M);
        float b2 = ex2(m2 - M);
        float inv = 1.f / (l_run * a + l2 * b2);
        float* orow = out + base + (size_t)(qt * QBLK + qb * 32 + ql) * FDIM;
        #pragma unroll
        for (int cb = 0; cb < 4; ++cb)
            #pragma unroll
            for (int r = 0; r < 16; ++r) {
                int e = cb * 32 + (r & 3) + 8 * (r >> 2) + 4 * hi2;
                orow[e] = (oacc[cb][r] * a + obuf[(qb * 32 + ql) * 132 + e] * b2) * inv;
            }
    }
}

extern "C" void kernel_launch(void* const* d_in, const int* in_sizes, int n_in,
                              void* d_out, int out_size, void* d_ws, size_t ws_size,
                              hipStream_t stream) {
    (void)in_sizes; (void)n_in; (void)out_size;
    const float* x  = (const float*)d_in[0];
    const float* Wq = (const float*)d_in[1];
    const float* Wk = (const float*)d_in[2];
    const float* Wv = (const float*)d_in[3];
    const float* bq = (const float*)d_in[4];
    const float* bk = (const float*)d_in[5];
    const float* bv = (const float*)d_in[6];

    const size_t elems = (size_t)NBH * SLEN * FDIM;          // 8,388,608 shorts/tensor
    const size_t wb_shorts = (size_t)3 * NH * FDIM * FDIM;   // 786,432 shorts
    short* Q  = (short*)d_ws;
    short* K  = Q + elems;
    short* Vt = K + elems;
    // Wb: after Vt if workspace allows, else scratch inside d_out (out is
    // fully rewritten by attn_fwd afterwards; stream-ordered, no hazard).
    short* Wb = (ws_size >= (3 * elems + wb_shorts) * sizeof(short))
              ? (Vt + elems) : (short*)d_out;

    wconv<<<dim3(192), 256, 0, stream>>>(Wq, Wk, Wv, Wb);
    qkv_fused<<<dim3(SLEN / 64, NBH), 256, 0, stream>>>(x, Wb, bq, bk, bv, Q, K, Vt);
    attn_fwd<<<dim3(NQT * NBH), 256, 0, stream>>>(Q, K, Vt, (float*)d_out);
}